// Round 4
// baseline (499.628 us; speedup 1.0000x reference)
//
#include <hip/hip_runtime.h>
#include <cstdint>
#include <cmath>

typedef __attribute__((ext_vector_type(4))) float f32x4;
typedef __attribute__((ext_vector_type(8))) short s16x8;

#define LOG2E 1.4426950408889634f

__device__ __forceinline__ unsigned short f2bf(float f) {
    unsigned int u = __float_as_uint(f);
    u += 0x7FFFu + ((u >> 16) & 1u);   // round-to-nearest-even
    return (unsigned short)(u >> 16);
}
__device__ __forceinline__ float bf2f(unsigned short s) {
    return __uint_as_float(((unsigned int)s) << 16);
}

// async global->LDS, 16B per lane. LDS dest is wave-uniform base + lane*16.
__device__ __forceinline__ void async_copy16(const void* g, void* l) {
    __builtin_amdgcn_global_load_lds(
        (const __attribute__((address_space(1))) unsigned int*)(uintptr_t)g,
        (__attribute__((address_space(3))) unsigned int*)(uintptr_t)l,
        16, 0, 0);
}

// ---------------- fp32 -> bf16 cast ----------------
__global__ __launch_bounds__(256) void cast_bf16_kernel(const float* __restrict__ in,
                                                        unsigned short* __restrict__ out,
                                                        int n4) {
    int i = blockIdx.x * 256 + threadIdx.x;
    if (i < n4) {
        float4 v = ((const float4*)in)[i];
        ushort4 o;
        o.x = f2bf(v.x); o.y = f2bf(v.y); o.z = f2bf(v.z); o.w = f2bf(v.w);
        ((ushort4*)out)[i] = o;
    }
}

// ---------------- barrier-free per-wave GEMM: C[M,N] = A[M,K]*B[N,K]^T + bias ----------------
// One wave per block, 64x64 tile, private 8KB LDS, single-buffered DMA staging.
// No __syncthreads: waits are wave-local s_waitcnt only -> no collective barrier drain.
// Chunk-XOR swizzle: LDS chunk (row, kc) holds global kc ^ ((row>>1)&3) so each
// consecutive-8-lane micro-phase of ds_read_b128 hits all 8 LDS 16B-groups.
template <bool BF16_OUT>
__global__ __launch_bounds__(64, 4) void gemm_wave(const unsigned short* __restrict__ A,
                                                   const unsigned short* __restrict__ B,
                                                   const float* __restrict__ bias,
                                                   void* __restrict__ Cout,
                                                   int M, int N, int K) {
    __shared__ unsigned short As[64 * 32];   // 4KB
    __shared__ unsigned short Bs[64 * 32];   // 4KB
    const int lane = threadIdx.x;            // 64-thread block = 1 wave
    const int m0 = blockIdx.y * 64;
    const int n0 = blockIdx.x * 64;
    const int fr = lane & 15;
    const int fg = lane >> 4;
    // staging: lane -> (row = 16*i + lane>>2, global chunk = (lane&3) ^ ((lane>>3)&3))
    const int srow = lane >> 2;
    const int scol = (((lane & 3) ^ ((lane >> 3) & 3)) * 8);
    // read-side swizzled k-chunk offset (per-lane constant)
    const int rofs = ((fg ^ ((fr >> 1) & 3)) * 8);

    f32x4 acc[4][4];
    const f32x4 zf = {0.f, 0.f, 0.f, 0.f};
    for (int r = 0; r < 4; ++r)
        for (int c = 0; c < 4; ++c) acc[r][c] = zf;

    const unsigned short* gA = A + (size_t)(m0 + srow) * K + scol;
    const unsigned short* gB = B + (size_t)(n0 + srow) * K + scol;

    for (int k0 = 0; k0 < K; k0 += 32) {
        // prior iteration's ds_reads must be complete before overwriting LDS
        asm volatile("s_waitcnt lgkmcnt(0)" ::: "memory");
        for (int i = 0; i < 4; ++i)
            async_copy16(gA + (size_t)i * 16 * K + k0, &As[i * 512]);
        for (int i = 0; i < 4; ++i)
            async_copy16(gB + (size_t)i * 16 * K + k0, &Bs[i * 512]);
        // wave-local drain of the DMA (no barrier needed: private buffer)
        asm volatile("s_waitcnt vmcnt(0)" ::: "memory");

        s16x8 af[4], bf[4];
        for (int r = 0; r < 4; ++r)
            af[r] = *(const s16x8*)&As[(r * 16 + fr) * 32 + rofs];
        for (int c = 0; c < 4; ++c)
            bf[c] = *(const s16x8*)&Bs[(c * 16 + fr) * 32 + rofs];
        for (int r = 0; r < 4; ++r)
            for (int c = 0; c < 4; ++c)
                acc[r][c] = __builtin_amdgcn_mfma_f32_16x16x32_bf16(af[r], bf[c], acc[r][c], 0, 0, 0);
    }

    // epilogue: C/D layout col=lane&15, row=(lane>>4)*4+reg
    const int rb = fg * 4;
    for (int c = 0; c < 4; ++c) {
        int col = n0 + c * 16 + fr;
        float bv = bias[col];
        for (int r = 0; r < 4; ++r) {
            int row = m0 + r * 16 + rb;
            for (int q = 0; q < 4; ++q) {
                float v = acc[r][c][q] + bv;
                if constexpr (BF16_OUT)
                    ((unsigned short*)Cout)[(size_t)(row + q) * N + col] = f2bf(v);
                else
                    ((float*)Cout)[(size_t)(row + q) * N + col] = v;
            }
        }
    }
}

// ---------------- RoPE in-place on q,k halves of qkv (bf16) ----------------
__global__ __launch_bounds__(256) void rope_kernel(unsigned short* __restrict__ qkv) {
    int g = blockIdx.x * 256 + threadIdx.x;  // 2048 * 1024 items
    int p = g >> 10;
    int i = g & 1023;
    int qk = i >> 9;
    int rem = i & 511;
    int hh = rem >> 4;
    int d = rem & 15;
    size_t base = (size_t)p * 7680 + qk * 2560 + hh * 80 + d;
    float x1 = bf2f(qkv[base]);
    float x2 = bf2f(qkv[base + 16]);
    float freq = expf(-(float)d * 0.57564627324851142f);  // ln(10000)/16
    float th = (float)p * freq;
    float s, c;
    sincosf(th, &s, &c);
    qkv[base]      = f2bf(x1 * c - x2 * s);
    qkv[base + 16] = f2bf(x1 * s + x2 * c);
}

// ---------------- pack K: qkv k-half -> Kp[h][key][96] (zero pad d>=80) ----------------
__global__ __launch_bounds__(256) void pack_k_kernel(const unsigned short* __restrict__ qkv,
                                                     unsigned short* __restrict__ Kp) {
    int g = blockIdx.x * 256 + threadIdx.x;  // 2048*32*12
    int c   = g % 12;
    int h   = (g / 12) & 31;
    int pos = g / 384;
    int d = c * 8;
    s16x8 v = {0, 0, 0, 0, 0, 0, 0, 0};
    if (d < 80)
        v = *(const s16x8*)(qkv + (size_t)pos * 7680 + 2560 + h * 80 + d);
    *(s16x8*)(Kp + ((size_t)h * 2048 + pos) * 96 + d) = v;
}

// ---------------- pack V^T tiled: qkv v-half -> Vp[h][kblk16][80][16] ----------------
__global__ __launch_bounds__(256) void pack_v_kernel(const unsigned short* __restrict__ qkv,
                                                     unsigned short* __restrict__ Vp) {
    int h  = blockIdx.x & 31;
    int g64 = blockIdx.x >> 5;           // 0..31
    int k0 = g64 * 64;
    int tid = threadIdx.x;
    for (int ci = tid; ci < 320; ci += 256) {   // (kbl 0..3) x (d 0..79)
        int d   = ci % 80;
        int kbl = ci / 80;
        unsigned short tmp[16];
        for (int j = 0; j < 16; ++j)
            tmp[j] = qkv[(size_t)(k0 + kbl * 16 + j) * 7680 + 5120 + h * 80 + d];
        unsigned short* dst = Vp + ((size_t)h * 128 + g64 * 4 + kbl) * 1280 + d * 16;
        *(s16x8*)dst       = *(const s16x8*)&tmp[0];
        *(s16x8*)(dst + 8) = *(const s16x8*)&tmp[8];
    }
}

// ---------------- flash attention v3: fixed-max softmax, split-K, pair-balanced ----------------
__global__ __launch_bounds__(256) void flash3_kernel(const unsigned short* __restrict__ qkv,
                                                     const unsigned short* __restrict__ Kp,
                                                     const unsigned short* __restrict__ Vp,
                                                     unsigned short* __restrict__ attn) {
    __shared__ unsigned short Pt[4][640];      // per-wave 16x40 P tile
    __shared__ float parts[2][16][84];         // odd-wave O partials (pitch 84)
    __shared__ float parts_l[2][16];           // odd-wave row-sum partials
    const int tid  = threadIdx.x;
    const int lane = tid & 63;
    const int wv   = tid >> 6;
    const int h = blockIdx.x & 31;
    const int p = blockIdx.x >> 5;             // 0..63
    const int s    = (wv < 2) ? p : (127 - p); // strip index (16 q rows)
    const int j    = wv & 1;                   // key-range half
    const int slot = wv >> 1;
    const int fr = lane & 15;
    const int fg = lane >> 4;
    const float k1 = 0.11180339887498949f * LOG2E;  // (1/sqrt(80)) * log2(e)
    const int sm16 = s * 16;

    const int n    = s + 1;                    // causal 16-key tiles
    const int half = (n + 1) >> 1;
    const int kstart = (j ? half : 0) * 16;
    const int kend   = (j ? n : half) * 16;

    s16x8 qf[3];
    {
        const unsigned short* qb = qkv + (size_t)(sm16 + fr) * 7680 + h * 80;
        const s16x8 zs = {0, 0, 0, 0, 0, 0, 0, 0};
        for (int sd = 0; sd < 3; ++sd) {
            int d = 32 * sd + fg * 8;
            qf[sd] = (d < 80) ? *(const s16x8*)(qb + d) : zs;
        }
    }

    f32x4 O[5];
    const f32x4 zf = {0.f, 0.f, 0.f, 0.f};
    for (int t = 0; t < 5; ++t) O[t] = zf;
    float rs[4] = {0.f, 0.f, 0.f, 0.f};

    const unsigned short* kptr = Kp + (size_t)h * 2048 * 96 + (size_t)(kstart + fr) * 96 + fg * 8;
    const unsigned short* vptr = Vp + (size_t)h * 128 * 1280 + (size_t)(kstart >> 4) * 1280
                                 + (fg >> 1) * 1280 + fr * 16 + (fg & 1) * 8;
    unsigned short* Pw = &Pt[wv][0];

    for (int k0 = kstart; k0 < kend; k0 += 32) {
        s16x8 kb[2][3];
        for (int g = 0; g < 2; ++g)
            for (int sd = 0; sd < 3; ++sd)
                kb[g][sd] = *(const s16x8*)(kptr + g * 1536 + sd * 32);
        s16x8 vb[5];
        for (int t = 0; t < 5; ++t)
            vb[t] = *(const s16x8*)(vptr + t * 256);

        f32x4 sa[2] = {zf, zf};
        for (int g = 0; g < 2; ++g)
            for (int sd = 0; sd < 3; ++sd)
                sa[g] = __builtin_amdgcn_mfma_f32_16x16x32_bf16(qf[sd], kb[g][sd], sa[g], 0, 0, 0);

        if (k0 + 32 > sm16 || k0 + 32 > kend) {
            for (int g = 0; g < 2; ++g)
                for (int r = 0; r < 4; ++r) {
                    int key  = k0 + g * 16 + fr;
                    int qrow = sm16 + fg * 4 + r;
                    if (key > qrow || key >= kend) sa[g][r] = -1e30f;
                }
        }

        float pr[2][4];
        for (int g = 0; g < 2; ++g)
            for (int r = 0; r < 4; ++r)
                pr[g][r] = __builtin_amdgcn_exp2f(sa[g][r] * k1);
        for (int r = 0; r < 4; ++r) rs[r] += pr[0][r] + pr[1][r];
        for (int g = 0; g < 2; ++g)
            for (int r = 0; r < 4; ++r)
                Pw[(fg * 4 + r) * 40 + g * 16 + fr] =
                    (unsigned short)(__float_as_uint(pr[g][r]) >> 16);

        s16x8 pa = *(const s16x8*)(Pw + fr * 40 + fg * 8);
        for (int t = 0; t < 5; ++t)
            O[t] = __builtin_amdgcn_mfma_f32_16x16x32_bf16(pa, vb[t], O[t], 0, 0, 0);

        kptr += 3072;   // 32 keys * 96
        vptr += 2560;   // 2 blocks * 1280
    }

    for (int r = 0; r < 4; ++r) {
        float v = rs[r];
        v += __shfl_xor(v, 1);
        v += __shfl_xor(v, 2);
        v += __shfl_xor(v, 4);
        v += __shfl_xor(v, 8);
        rs[r] = v;
    }

    if (j) {
        for (int t = 0; t < 5; ++t)
            for (int r = 0; r < 4; ++r)
                parts[slot][fg * 4 + r][t * 16 + fr] = O[t][r];
        if (fr == 0)
            for (int r = 0; r < 4; ++r) parts_l[slot][fg * 4 + r] = rs[r];
    }
    __syncthreads();
    if (!j) {
        for (int r = 0; r < 4; ++r) {
            float rl = 1.0f / (rs[r] + parts_l[slot][fg * 4 + r]);
            int row = sm16 + fg * 4 + r;
            for (int t = 0; t < 5; ++t) {
                float v = (O[t][r] + parts[slot][fg * 4 + r][t * 16 + fr]) * rl;
                attn[(size_t)row * 2560 + h * 80 + t * 16 + fr] = f2bf(v);
            }
        }
    }
}

extern "C" void kernel_launch(void* const* d_in, const int* in_sizes, int n_in,
                              void* d_out, int out_size, void* d_ws, size_t ws_size,
                              hipStream_t stream) {
    const float* x    = (const float*)d_in[0];
    const float* wqkv = (const float*)d_in[1];
    const float* bqkv = (const float*)d_in[2];
    const float* outw = (const float*)d_in[3];
    const float* outb = (const float*)d_in[4];

    unsigned short* xb    = (unsigned short*)d_ws;                  // 2048*2560
    unsigned short* wqkvb = xb + (size_t)2048 * 2560;               // 7680*2560 (dead after gemm1)
    unsigned short* Kp    = wqkvb;                                  // 32*2048*96   (aliases wqkvb)
    unsigned short* Vp    = wqkvb + (size_t)32 * 2048 * 96;         // 32*128*1280  (aliases wqkvb)
    unsigned short* outwb = wqkvb + (size_t)7680 * 2560;            // 2560*2560
    unsigned short* qkvb  = outwb + (size_t)2560 * 2560;            // 2048*7680
    unsigned short* attnb = qkvb  + (size_t)2048 * 7680;            // 2048*2560
    float* out = (float*)d_out;

    cast_bf16_kernel<<<2048 * 2560 / 4 / 256, 256, 0, stream>>>(x, xb, 2048 * 2560 / 4);
    cast_bf16_kernel<<<7680 * 2560 / 4 / 256, 256, 0, stream>>>(wqkv, wqkvb, 7680 * 2560 / 4);
    cast_bf16_kernel<<<2560 * 2560 / 4 / 256, 256, 0, stream>>>(outw, outwb, 2560 * 2560 / 4);

    gemm_wave<true><<<dim3(7680 / 64, 2048 / 64), 64, 0, stream>>>(
        xb, wqkvb, bqkv, (void*)qkvb, 2048, 7680, 2560);

    rope_kernel<<<2048 * 1024 / 256, 256, 0, stream>>>(qkvb);

    pack_k_kernel<<<2048 * 384 / 256, 256, 0, stream>>>(qkvb, Kp);
    pack_v_kernel<<<32 * 32, 256, 0, stream>>>(qkvb, Vp);

    flash3_kernel<<<2048, 256, 0, stream>>>(qkvb, Kp, Vp, attnb);

    gemm_wave<false><<<dim3(2560 / 64, 2048 / 64), 64, 0, stream>>>(
        attnb, outwb, outb, (void*)out, 2048, 2560, 2560);
}

// Round 5
// 492.208 us; speedup vs baseline: 1.0151x; 1.0151x over previous
//
#include <hip/hip_runtime.h>
#include <cstdint>
#include <cmath>

typedef __attribute__((ext_vector_type(4))) float f32x4;
typedef __attribute__((ext_vector_type(8))) short s16x8;

#define LOG2E 1.4426950408889634f

__device__ __forceinline__ unsigned short f2bf(float f) {
    unsigned int u = __float_as_uint(f);
    u += 0x7FFFu + ((u >> 16) & 1u);   // round-to-nearest-even
    return (unsigned short)(u >> 16);
}
__device__ __forceinline__ float bf2f(unsigned short s) {
    return __uint_as_float(((unsigned int)s) << 16);
}

// async global->LDS, 16B per lane. LDS dest is wave-uniform base + lane*16.
__device__ __forceinline__ void async_copy16(const void* g, void* l) {
    __builtin_amdgcn_global_load_lds(
        (const __attribute__((address_space(1))) unsigned int*)(uintptr_t)g,
        (__attribute__((address_space(3))) unsigned int*)(uintptr_t)l,
        16, 0, 0);
}

// ---------------- fp32 -> bf16 cast ----------------
__global__ __launch_bounds__(256) void cast_bf16_kernel(const float* __restrict__ in,
                                                        unsigned short* __restrict__ out,
                                                        int n4) {
    int i = blockIdx.x * 256 + threadIdx.x;
    if (i < n4) {
        float4 v = ((const float4*)in)[i];
        ushort4 o;
        o.x = f2bf(v.x); o.y = f2bf(v.y); o.z = f2bf(v.z); o.w = f2bf(v.w);
        ((ushort4*)out)[i] = o;
    }
}

// ---------------- GEMM: C[M,N] = A[M,K] * B[N,K]^T + bias ----------------
// 128x128 tile, 4 waves (64x64 each), global_load_lds staging.
// Chunk-XOR swizzle (verified conflict-free in r4): staging lane fetches global
// k-chunk (lane&3)^((lane>>3)&3); reader uses slot fg^((fr>>1)&3). Each 8-lane
// micro-phase of ds_read_b128 then hits all 8 LDS 16B-groups.
// ATOMIC: accumulate into fp32 Cout via unsafeAtomicAdd over K-range [kstart,kend).
template <bool BF16_OUT, bool ATOMIC>
__global__ __launch_bounds__(256) void gemm_bt(const unsigned short* __restrict__ A,
                                               const unsigned short* __restrict__ B,
                                               const float* __restrict__ bias,
                                               void* __restrict__ Cout,
                                               int M, int N, int K) {
    __shared__ unsigned short As[128 * 32];
    __shared__ unsigned short Bs[128 * 32];
    const int tid  = threadIdx.x;
    const int lane = tid & 63;
    const int wv   = tid >> 6;
    const int m0 = blockIdx.y * 128;
    const int n0 = blockIdx.x * 128;
    const int w_row = (wv >> 1) * 64;
    const int w_col = (wv & 1) * 64;
    const int fr = lane & 15;
    const int fg = lane >> 4;
    const int srow = lane >> 2;
    const int scol = (((lane & 3) ^ ((lane >> 3) & 3)) * 8);   // swizzled staging chunk
    const int rofs = ((fg ^ ((fr >> 1) & 3)) * 8);             // swizzled read offset
    const int c0 = wv * 2;

    int kstart = 0, kend = K;
    if (ATOMIC) {
        kstart = blockIdx.z * (K >> 1);
        kend   = kstart + (K >> 1);
    }

    f32x4 acc[4][4];
    const f32x4 zf = {0.f, 0.f, 0.f, 0.f};
    for (int r = 0; r < 4; ++r)
        for (int c = 0; c < 4; ++c) acc[r][c] = zf;

    for (int k0 = kstart; k0 < kend; k0 += 32) {
        for (int c = c0; c < c0 + 2; ++c) {
            const unsigned short* gA = A + (size_t)(m0 + c * 16 + srow) * K + (k0 + scol);
            async_copy16(gA, &As[c * 512]);
            const unsigned short* gB = B + (size_t)(n0 + c * 16 + srow) * K + (k0 + scol);
            async_copy16(gB, &Bs[c * 512]);
        }
        __syncthreads();
        s16x8 af[4], bf[4];
        for (int r = 0; r < 4; ++r)
            af[r] = *(const s16x8*)&As[(w_row + r * 16 + fr) * 32 + rofs];
        for (int c = 0; c < 4; ++c)
            bf[c] = *(const s16x8*)&Bs[(w_col + c * 16 + fr) * 32 + rofs];
        for (int r = 0; r < 4; ++r)
            for (int c = 0; c < 4; ++c)
                acc[r][c] = __builtin_amdgcn_mfma_f32_16x16x32_bf16(af[r], bf[c], acc[r][c], 0, 0, 0);
        __syncthreads();
    }

    // epilogue: C/D layout col=lane&15, row=(lane>>4)*4+reg
    const int rb = (lane >> 4) * 4;
    const bool addb = !ATOMIC || blockIdx.z == 0;
    for (int c = 0; c < 4; ++c) {
        int col = n0 + w_col + c * 16 + fr;
        float bv = addb ? bias[col] : 0.f;
        for (int r = 0; r < 4; ++r) {
            int row = m0 + w_row + r * 16 + rb;
            for (int q = 0; q < 4; ++q) {
                float v = acc[r][c][q] + bv;
                if constexpr (ATOMIC) {
                    unsafeAtomicAdd(&((float*)Cout)[(size_t)(row + q) * N + col], v);
                } else if constexpr (BF16_OUT) {
                    ((unsigned short*)Cout)[(size_t)(row + q) * N + col] = f2bf(v);
                } else {
                    ((float*)Cout)[(size_t)(row + q) * N + col] = v;
                }
            }
        }
    }
}

// ---------------- RoPE in-place on q-half only (k handled in rope_pack_k) ----------------
// Each lane owns full pairs (reads+writes both halves) -> no cross-lane race.
__global__ __launch_bounds__(256) void rope_q_kernel(unsigned short* __restrict__ qkv) {
    int g = blockIdx.x * 256 + threadIdx.x;  // 2048*32*2 items
    int c = g & 1;            // half-chunk: pairs d0..d0+7
    int h = (g >> 1) & 31;
    int p = g >> 6;
    size_t base = (size_t)p * 7680 + h * 80 + c * 8;
    s16x8 x1v = *(const s16x8*)(qkv + base);
    s16x8 x2v = *(const s16x8*)(qkv + base + 16);
    s16x8 o1, o2;
    for (int j = 0; j < 8; ++j) {
        int dp = c * 8 + j;
        float freq = expf(-(float)dp * 0.57564627324851142f);  // ln(10000)/16
        float sn, cs;
        sincosf((float)p * freq, &sn, &cs);
        float x1 = bf2f((unsigned short)x1v[j]);
        float x2 = bf2f((unsigned short)x2v[j]);
        o1[j] = (short)f2bf(x1 * cs - x2 * sn);
        o2[j] = (short)f2bf(x1 * sn + x2 * cs);
    }
    *(s16x8*)(qkv + base)      = o1;
    *(s16x8*)(qkv + base + 16) = o2;
}

// ---------------- fused k-RoPE + pack: qkv k-half -> Kp[h][key][96] ----------------
__global__ __launch_bounds__(256) void rope_pack_k_kernel(const unsigned short* __restrict__ qkv,
                                                          unsigned short* __restrict__ Kp) {
    int g = blockIdx.x * 256 + threadIdx.x;  // 2048*32*12
    int c   = g % 12;
    int h   = (g / 12) & 31;
    int pos = g / 384;
    int d0 = c * 8;
    const unsigned short* kb = qkv + (size_t)pos * 7680 + 2560 + h * 80;
    s16x8 v = {0, 0, 0, 0, 0, 0, 0, 0};
    if (c >= 4) {
        if (d0 < 80) v = *(const s16x8*)(kb + d0);
    } else if (c < 2) {          // x1 side: out = x1*cos - x2*sin
        s16x8 x1v = *(const s16x8*)(kb + d0);
        s16x8 x2v = *(const s16x8*)(kb + d0 + 16);
        for (int j = 0; j < 8; ++j) {
            int dp = d0 + j;
            float freq = expf(-(float)dp * 0.57564627324851142f);
            float sn, cs;
            sincosf((float)pos * freq, &sn, &cs);
            v[j] = (short)f2bf(bf2f((unsigned short)x1v[j]) * cs -
                               bf2f((unsigned short)x2v[j]) * sn);
        }
    } else {                     // x2 side: out = x1*sin + x2*cos
        s16x8 x1v = *(const s16x8*)(kb + d0 - 16);
        s16x8 x2v = *(const s16x8*)(kb + d0);
        for (int j = 0; j < 8; ++j) {
            int dp = d0 - 16 + j;
            float freq = expf(-(float)dp * 0.57564627324851142f);
            float sn, cs;
            sincosf((float)pos * freq, &sn, &cs);
            v[j] = (short)f2bf(bf2f((unsigned short)x1v[j]) * sn +
                               bf2f((unsigned short)x2v[j]) * cs);
        }
    }
    *(s16x8*)(Kp + ((size_t)h * 2048 + pos) * 96 + d0) = v;
}

// ---------------- pack V^T tiled: qkv v-half -> Vp[h][kblk16][80][16] ----------------
__global__ __launch_bounds__(256) void pack_v_kernel(const unsigned short* __restrict__ qkv,
                                                     unsigned short* __restrict__ Vp) {
    int h  = blockIdx.x & 31;
    int g64 = blockIdx.x >> 5;           // 0..31
    int k0 = g64 * 64;
    int tid = threadIdx.x;
    for (int ci = tid; ci < 320; ci += 256) {   // (kbl 0..3) x (d 0..79)
        int d   = ci % 80;
        int kbl = ci / 80;
        unsigned short tmp[16];
        for (int j = 0; j < 16; ++j)
            tmp[j] = qkv[(size_t)(k0 + kbl * 16 + j) * 7680 + 5120 + h * 80 + d];
        unsigned short* dst = Vp + ((size_t)h * 128 + g64 * 4 + kbl) * 1280 + d * 16;
        *(s16x8*)dst       = *(const s16x8*)&tmp[0];
        *(s16x8*)(dst + 8) = *(const s16x8*)&tmp[8];
    }
}

// ---------------- flash attention v3: fixed-max softmax, split-K, pair-balanced ----------------
__global__ __launch_bounds__(256) void flash3_kernel(const unsigned short* __restrict__ qkv,
                                                     const unsigned short* __restrict__ Kp,
                                                     const unsigned short* __restrict__ Vp,
                                                     unsigned short* __restrict__ attn) {
    __shared__ unsigned short Pt[4][640];      // per-wave 16x40 P tile
    __shared__ float parts[2][16][84];         // odd-wave O partials (pitch 84)
    __shared__ float parts_l[2][16];           // odd-wave row-sum partials
    const int tid  = threadIdx.x;
    const int lane = tid & 63;
    const int wv   = tid >> 6;
    const int h = blockIdx.x & 31;
    const int p = blockIdx.x >> 5;             // 0..63
    const int s    = (wv < 2) ? p : (127 - p); // strip index (16 q rows)
    const int j    = wv & 1;                   // key-range half
    const int slot = wv >> 1;
    const int fr = lane & 15;
    const int fg = lane >> 4;
    const float k1 = 0.11180339887498949f * LOG2E;  // (1/sqrt(80)) * log2(e)
    const int sm16 = s * 16;

    const int n    = s + 1;                    // causal 16-key tiles
    const int half = (n + 1) >> 1;
    const int kstart = (j ? half : 0) * 16;
    const int kend   = (j ? n : half) * 16;

    s16x8 qf[3];
    {
        const unsigned short* qb = qkv + (size_t)(sm16 + fr) * 7680 + h * 80;
        const s16x8 zs = {0, 0, 0, 0, 0, 0, 0, 0};
        for (int sd = 0; sd < 3; ++sd) {
            int d = 32 * sd + fg * 8;
            qf[sd] = (d < 80) ? *(const s16x8*)(qb + d) : zs;
        }
    }

    f32x4 O[5];
    const f32x4 zf = {0.f, 0.f, 0.f, 0.f};
    for (int t = 0; t < 5; ++t) O[t] = zf;
    float rs[4] = {0.f, 0.f, 0.f, 0.f};

    const unsigned short* kptr = Kp + (size_t)h * 2048 * 96 + (size_t)(kstart + fr) * 96 + fg * 8;
    const unsigned short* vptr = Vp + (size_t)h * 128 * 1280 + (size_t)(kstart >> 4) * 1280
                                 + (fg >> 1) * 1280 + fr * 16 + (fg & 1) * 8;
    unsigned short* Pw = &Pt[wv][0];

    for (int k0 = kstart; k0 < kend; k0 += 32) {
        s16x8 kb[2][3];
        for (int g = 0; g < 2; ++g)
            for (int sd = 0; sd < 3; ++sd)
                kb[g][sd] = *(const s16x8*)(kptr + g * 1536 + sd * 32);
        s16x8 vb[5];
        for (int t = 0; t < 5; ++t)
            vb[t] = *(const s16x8*)(vptr + t * 256);

        f32x4 sa[2] = {zf, zf};
        for (int g = 0; g < 2; ++g)
            for (int sd = 0; sd < 3; ++sd)
                sa[g] = __builtin_amdgcn_mfma_f32_16x16x32_bf16(qf[sd], kb[g][sd], sa[g], 0, 0, 0);

        if (k0 + 32 > sm16 || k0 + 32 > kend) {
            for (int g = 0; g < 2; ++g)
                for (int r = 0; r < 4; ++r) {
                    int key  = k0 + g * 16 + fr;
                    int qrow = sm16 + fg * 4 + r;
                    if (key > qrow || key >= kend) sa[g][r] = -1e30f;
                }
        }

        float pr[2][4];
        for (int g = 0; g < 2; ++g)
            for (int r = 0; r < 4; ++r)
                pr[g][r] = __builtin_amdgcn_exp2f(sa[g][r] * k1);
        for (int r = 0; r < 4; ++r) rs[r] += pr[0][r] + pr[1][r];
        for (int g = 0; g < 2; ++g)
            for (int r = 0; r < 4; ++r)
                Pw[(fg * 4 + r) * 40 + g * 16 + fr] =
                    (unsigned short)(__float_as_uint(pr[g][r]) >> 16);

        s16x8 pa = *(const s16x8*)(Pw + fr * 40 + fg * 8);
        for (int t = 0; t < 5; ++t)
            O[t] = __builtin_amdgcn_mfma_f32_16x16x32_bf16(pa, vb[t], O[t], 0, 0, 0);

        kptr += 3072;   // 32 keys * 96
        vptr += 2560;   // 2 blocks * 1280
    }

    for (int r = 0; r < 4; ++r) {
        float v = rs[r];
        v += __shfl_xor(v, 1);
        v += __shfl_xor(v, 2);
        v += __shfl_xor(v, 4);
        v += __shfl_xor(v, 8);
        rs[r] = v;
    }

    if (j) {
        for (int t = 0; t < 5; ++t)
            for (int r = 0; r < 4; ++r)
                parts[slot][fg * 4 + r][t * 16 + fr] = O[t][r];
        if (fr == 0)
            for (int r = 0; r < 4; ++r) parts_l[slot][fg * 4 + r] = rs[r];
    }
    __syncthreads();
    if (!j) {
        for (int r = 0; r < 4; ++r) {
            float rl = 1.0f / (rs[r] + parts_l[slot][fg * 4 + r]);
            int row = sm16 + fg * 4 + r;
            for (int t = 0; t < 5; ++t) {
                float v = (O[t][r] + parts[slot][fg * 4 + r][t * 16 + fr]) * rl;
                attn[(size_t)row * 2560 + h * 80 + t * 16 + fr] = f2bf(v);
            }
        }
    }
}

extern "C" void kernel_launch(void* const* d_in, const int* in_sizes, int n_in,
                              void* d_out, int out_size, void* d_ws, size_t ws_size,
                              hipStream_t stream) {
    const float* x    = (const float*)d_in[0];
    const float* wqkv = (const float*)d_in[1];
    const float* bqkv = (const float*)d_in[2];
    const float* outw = (const float*)d_in[3];
    const float* outb = (const float*)d_in[4];

    unsigned short* xb    = (unsigned short*)d_ws;                  // 2048*2560
    unsigned short* wqkvb = xb + (size_t)2048 * 2560;               // 7680*2560 (dead after gemm1)
    unsigned short* Kp    = wqkvb;                                  // 32*2048*96   (aliases wqkvb)
    unsigned short* Vp    = wqkvb + (size_t)32 * 2048 * 96;         // 32*128*1280  (aliases wqkvb)
    unsigned short* outwb = wqkvb + (size_t)7680 * 2560;            // 2560*2560
    unsigned short* qkvb  = outwb + (size_t)2560 * 2560;            // 2048*7680
    unsigned short* attnb = qkvb  + (size_t)2048 * 7680;            // 2048*2560
    float* out = (float*)d_out;

    cast_bf16_kernel<<<2048 * 2560 / 4 / 256, 256, 0, stream>>>(x, xb, 2048 * 2560 / 4);
    cast_bf16_kernel<<<7680 * 2560 / 4 / 256, 256, 0, stream>>>(wqkv, wqkvb, 7680 * 2560 / 4);
    cast_bf16_kernel<<<2560 * 2560 / 4 / 256, 256, 0, stream>>>(outw, outwb, 2560 * 2560 / 4);

    gemm_bt<true, false><<<dim3(7680 / 128, 2048 / 128), 256, 0, stream>>>(
        xb, wqkvb, bqkv, (void*)qkvb, 2048, 7680, 2560);

    rope_q_kernel<<<2048 * 64 / 256, 256, 0, stream>>>(qkvb);
    rope_pack_k_kernel<<<2048 * 384 / 256, 256, 0, stream>>>(qkvb, Kp);
    pack_v_kernel<<<32 * 32, 256, 0, stream>>>(qkvb, Vp);

    flash3_kernel<<<2048, 256, 0, stream>>>(qkvb, Kp, Vp, attnb);

    // gemm2: split-K=2, fp32 atomic accumulate into zeroed d_out
    hipMemsetAsync(d_out, 0, (size_t)2048 * 2560 * 4, stream);
    gemm_bt<false, true><<<dim3(2560 / 128, 2048 / 128, 2), 256, 0, stream>>>(
        attnb, outwb, outb, (void*)out, 2048, 2560, 2560);
}

// Round 6
// 442.250 us; speedup vs baseline: 1.1297x; 1.1130x over previous
//
#include <hip/hip_runtime.h>
#include <cstdint>
#include <cmath>

typedef __attribute__((ext_vector_type(4))) float f32x4;
typedef __attribute__((ext_vector_type(8))) short s16x8;

#define LOG2E 1.4426950408889634f

__device__ __forceinline__ unsigned short f2bf(float f) {
    unsigned int u = __float_as_uint(f);
    u += 0x7FFFu + ((u >> 16) & 1u);   // round-to-nearest-even
    return (unsigned short)(u >> 16);
}
__device__ __forceinline__ float bf2f(unsigned short s) {
    return __uint_as_float(((unsigned int)s) << 16);
}

// async global->LDS, 16B per lane. LDS dest is wave-uniform base + lane*16.
__device__ __forceinline__ void async_copy16(const void* g, void* l) {
    __builtin_amdgcn_global_load_lds(
        (const __attribute__((address_space(1))) unsigned int*)(uintptr_t)g,
        (__attribute__((address_space(3))) unsigned int*)(uintptr_t)l,
        16, 0, 0);
}

// ---------------- fp32 -> bf16 cast ----------------
__global__ __launch_bounds__(256) void cast_bf16_kernel(const float* __restrict__ in,
                                                        unsigned short* __restrict__ out,
                                                        int n4) {
    int i = blockIdx.x * 256 + threadIdx.x;
    if (i < n4) {
        float4 v = ((const float4*)in)[i];
        ushort4 o;
        o.x = f2bf(v.x); o.y = f2bf(v.y); o.z = f2bf(v.z); o.w = f2bf(v.w);
        ((ushort4*)out)[i] = o;
    }
}

// ---------------- GEMM: C[M,N] = A[M,K] * B[N,K]^T + bias ----------------
// 128x128 tile, BK=64 (40 barriers instead of 80 at K=2560 — amortize the
// vmcnt(0)+barrier drain), 4 waves each 64x64. global_load_lds staging.
// XOR swizzle (mod-8): LDS slot (row, sc) holds global k-chunk sc ^ (row&7);
// reader for K-step s uses chunk ((s*4+fg) ^ (fr&7)) — every 8-lane micro-phase
// of ds_read_b128 hits 8 distinct 16B groups (verified 0 conflicts in r4/r5).
template <bool BF16_OUT>
__global__ __launch_bounds__(256) void gemm_bt(const unsigned short* __restrict__ A,
                                               const unsigned short* __restrict__ B,
                                               const float* __restrict__ bias,
                                               void* __restrict__ Cout,
                                               int M, int N, int K) {
    __shared__ unsigned short As[128 * 64];   // 16 KB
    __shared__ unsigned short Bs[128 * 64];   // 16 KB
    const int tid  = threadIdx.x;
    const int lane = tid & 63;
    const int wv   = tid >> 6;
    const int m0 = blockIdx.y * 128;
    const int n0 = blockIdx.x * 128;
    const int w_row = (wv >> 1) * 64;
    const int w_col = (wv & 1) * 64;
    const int fr = lane & 15;
    const int fg = lane >> 4;
    // staging: copy i covers rows [wv*32 + i*8, +8); lane -> row += lane>>3,
    // fetches global chunk (lane&7) ^ ((lane>>3)&7)  (8 elems)
    const int srow = lane >> 3;
    const int scol = ((lane & 7) ^ srow) * 8;
    // read-side swizzled chunk offsets (elements) for K-steps s=0,1
    const int rofs0 = ((fg ^ (fr & 7))) * 8;
    const int rofs1 = rofs0 ^ 32;

    f32x4 acc[4][4];
    const f32x4 zf = {0.f, 0.f, 0.f, 0.f};
    for (int r = 0; r < 4; ++r)
        for (int c = 0; c < 4; ++c) acc[r][c] = zf;

    const unsigned short* gA = A + (size_t)(m0 + wv * 32 + srow) * K + scol;
    const unsigned short* gB = B + (size_t)(n0 + wv * 32 + srow) * K + scol;
    const int ldsbase = (wv * 32 + srow) * 64;   // element offset of this lane's dest row

    for (int k0 = 0; k0 < K; k0 += 64) {
        for (int i = 0; i < 4; ++i)
            async_copy16(gA + (size_t)i * 8 * K + k0, &As[(wv * 32 + i * 8) * 64]);
        for (int i = 0; i < 4; ++i)
            async_copy16(gB + (size_t)i * 8 * K + k0, &Bs[(wv * 32 + i * 8) * 64]);
        __syncthreads();
        // K-step 0
        {
            s16x8 af[4], bf[4];
            for (int r = 0; r < 4; ++r)
                af[r] = *(const s16x8*)&As[(w_row + r * 16 + fr) * 64 + rofs0];
            for (int c = 0; c < 4; ++c)
                bf[c] = *(const s16x8*)&Bs[(w_col + c * 16 + fr) * 64 + rofs0];
            for (int r = 0; r < 4; ++r)
                for (int c = 0; c < 4; ++c)
                    acc[r][c] = __builtin_amdgcn_mfma_f32_16x16x32_bf16(af[r], bf[c], acc[r][c], 0, 0, 0);
        }
        // K-step 1
        {
            s16x8 af[4], bf[4];
            for (int r = 0; r < 4; ++r)
                af[r] = *(const s16x8*)&As[(w_row + r * 16 + fr) * 64 + rofs1];
            for (int c = 0; c < 4; ++c)
                bf[c] = *(const s16x8*)&Bs[(w_col + c * 16 + fr) * 64 + rofs1];
            for (int r = 0; r < 4; ++r)
                for (int c = 0; c < 4; ++c)
                    acc[r][c] = __builtin_amdgcn_mfma_f32_16x16x32_bf16(af[r], bf[c], acc[r][c], 0, 0, 0);
        }
        __syncthreads();
    }

    // epilogue: C/D layout col=lane&15, row=(lane>>4)*4+reg
    const int rb = (lane >> 4) * 4;
    for (int c = 0; c < 4; ++c) {
        int col = n0 + w_col + c * 16 + fr;
        float bv = bias[col];
        for (int r = 0; r < 4; ++r) {
            int row = m0 + w_row + r * 16 + rb;
            for (int q = 0; q < 4; ++q) {
                float v = acc[r][c][q] + bv;
                if constexpr (BF16_OUT)
                    ((unsigned short*)Cout)[(size_t)(row + q) * N + col] = f2bf(v);
                else
                    ((float*)Cout)[(size_t)(row + q) * N + col] = v;
            }
        }
    }
}

// ---------------- RoPE in-place on q-half only (k handled in rope_pack_k) ----------------
__global__ __launch_bounds__(256) void rope_q_kernel(unsigned short* __restrict__ qkv) {
    int g = blockIdx.x * 256 + threadIdx.x;  // 2048*32*2 items
    int c = g & 1;            // half-chunk: pairs d0..d0+7
    int h = (g >> 1) & 31;
    int p = g >> 6;
    size_t base = (size_t)p * 7680 + h * 80 + c * 8;
    s16x8 x1v = *(const s16x8*)(qkv + base);
    s16x8 x2v = *(const s16x8*)(qkv + base + 16);
    s16x8 o1, o2;
    for (int j = 0; j < 8; ++j) {
        int dp = c * 8 + j;
        float freq = expf(-(float)dp * 0.57564627324851142f);  // ln(10000)/16
        float sn, cs;
        sincosf((float)p * freq, &sn, &cs);
        float x1 = bf2f((unsigned short)x1v[j]);
        float x2 = bf2f((unsigned short)x2v[j]);
        o1[j] = (short)f2bf(x1 * cs - x2 * sn);
        o2[j] = (short)f2bf(x1 * sn + x2 * cs);
    }
    *(s16x8*)(qkv + base)      = o1;
    *(s16x8*)(qkv + base + 16) = o2;
}

// ---------------- fused k-RoPE + pack: qkv k-half -> Kp[h][key][96] ----------------
__global__ __launch_bounds__(256) void rope_pack_k_kernel(const unsigned short* __restrict__ qkv,
                                                          unsigned short* __restrict__ Kp) {
    int g = blockIdx.x * 256 + threadIdx.x;  // 2048*32*12
    int c   = g % 12;
    int h   = (g / 12) & 31;
    int pos = g / 384;
    int d0 = c * 8;
    const unsigned short* kb = qkv + (size_t)pos * 7680 + 2560 + h * 80;
    s16x8 v = {0, 0, 0, 0, 0, 0, 0, 0};
    if (c >= 4) {
        if (d0 < 80) v = *(const s16x8*)(kb + d0);
    } else if (c < 2) {          // x1 side: out = x1*cos - x2*sin
        s16x8 x1v = *(const s16x8*)(kb + d0);
        s16x8 x2v = *(const s16x8*)(kb + d0 + 16);
        for (int j = 0; j < 8; ++j) {
            int dp = d0 + j;
            float freq = expf(-(float)dp * 0.57564627324851142f);
            float sn, cs;
            sincosf((float)pos * freq, &sn, &cs);
            v[j] = (short)f2bf(bf2f((unsigned short)x1v[j]) * cs -
                               bf2f((unsigned short)x2v[j]) * sn);
        }
    } else {                     // x2 side: out = x1*sin + x2*cos
        s16x8 x1v = *(const s16x8*)(kb + d0 - 16);
        s16x8 x2v = *(const s16x8*)(kb + d0);
        for (int j = 0; j < 8; ++j) {
            int dp = d0 - 16 + j;
            float freq = expf(-(float)dp * 0.57564627324851142f);
            float sn, cs;
            sincosf((float)pos * freq, &sn, &cs);
            v[j] = (short)f2bf(bf2f((unsigned short)x1v[j]) * sn +
                               bf2f((unsigned short)x2v[j]) * cs);
        }
    }
    *(s16x8*)(Kp + ((size_t)h * 2048 + pos) * 96 + d0) = v;
}

// ---------------- pack V^T tiled: qkv v-half -> Vp[h][kblk16][80][16] ----------------
__global__ __launch_bounds__(256) void pack_v_kernel(const unsigned short* __restrict__ qkv,
                                                     unsigned short* __restrict__ Vp) {
    int h  = blockIdx.x & 31;
    int g64 = blockIdx.x >> 5;           // 0..31
    int k0 = g64 * 64;
    int tid = threadIdx.x;
    for (int ci = tid; ci < 320; ci += 256) {   // (kbl 0..3) x (d 0..79)
        int d   = ci % 80;
        int kbl = ci / 80;
        unsigned short tmp[16];
        for (int j = 0; j < 16; ++j)
            tmp[j] = qkv[(size_t)(k0 + kbl * 16 + j) * 7680 + 5120 + h * 80 + d];
        unsigned short* dst = Vp + ((size_t)h * 128 + g64 * 4 + kbl) * 1280 + d * 16;
        *(s16x8*)dst       = *(const s16x8*)&tmp[0];
        *(s16x8*)(dst + 8) = *(const s16x8*)&tmp[8];
    }
}

// ---------------- flash attention v3: fixed-max softmax, split-K, pair-balanced ----------------
__global__ __launch_bounds__(256) void flash3_kernel(const unsigned short* __restrict__ qkv,
                                                     const unsigned short* __restrict__ Kp,
                                                     const unsigned short* __restrict__ Vp,
                                                     unsigned short* __restrict__ attn) {
    __shared__ unsigned short Pt[4][640];      // per-wave 16x40 P tile
    __shared__ float parts[2][16][84];         // odd-wave O partials (pitch 84)
    __shared__ float parts_l[2][16];           // odd-wave row-sum partials
    const int tid  = threadIdx.x;
    const int lane = tid & 63;
    const int wv   = tid >> 6;
    const int h = blockIdx.x & 31;
    const int p = blockIdx.x >> 5;             // 0..63
    const int s    = (wv < 2) ? p : (127 - p); // strip index (16 q rows)
    const int j    = wv & 1;                   // key-range half
    const int slot = wv >> 1;
    const int fr = lane & 15;
    const int fg = lane >> 4;
    const float k1 = 0.11180339887498949f * LOG2E;  // (1/sqrt(80)) * log2(e)
    const int sm16 = s * 16;

    const int n    = s + 1;                    // causal 16-key tiles
    const int half = (n + 1) >> 1;
    const int kstart = (j ? half : 0) * 16;
    const int kend   = (j ? n : half) * 16;

    s16x8 qf[3];
    {
        const unsigned short* qb = qkv + (size_t)(sm16 + fr) * 7680 + h * 80;
        const s16x8 zs = {0, 0, 0, 0, 0, 0, 0, 0};
        for (int sd = 0; sd < 3; ++sd) {
            int d = 32 * sd + fg * 8;
            qf[sd] = (d < 80) ? *(const s16x8*)(qb + d) : zs;
        }
    }

    f32x4 O[5];
    const f32x4 zf = {0.f, 0.f, 0.f, 0.f};
    for (int t = 0; t < 5; ++t) O[t] = zf;
    float rs[4] = {0.f, 0.f, 0.f, 0.f};

    const unsigned short* kptr = Kp + (size_t)h * 2048 * 96 + (size_t)(kstart + fr) * 96 + fg * 8;
    const unsigned short* vptr = Vp + (size_t)h * 128 * 1280 + (size_t)(kstart >> 4) * 1280
                                 + (fg >> 1) * 1280 + fr * 16 + (fg & 1) * 8;
    unsigned short* Pw = &Pt[wv][0];

    for (int k0 = kstart; k0 < kend; k0 += 32) {
        s16x8 kb[2][3];
        for (int g = 0; g < 2; ++g)
            for (int sd = 0; sd < 3; ++sd)
                kb[g][sd] = *(const s16x8*)(kptr + g * 1536 + sd * 32);
        s16x8 vb[5];
        for (int t = 0; t < 5; ++t)
            vb[t] = *(const s16x8*)(vptr + t * 256);

        f32x4 sa[2] = {zf, zf};
        for (int g = 0; g < 2; ++g)
            for (int sd = 0; sd < 3; ++sd)
                sa[g] = __builtin_amdgcn_mfma_f32_16x16x32_bf16(qf[sd], kb[g][sd], sa[g], 0, 0, 0);

        if (k0 + 32 > sm16 || k0 + 32 > kend) {
            for (int g = 0; g < 2; ++g)
                for (int r = 0; r < 4; ++r) {
                    int key  = k0 + g * 16 + fr;
                    int qrow = sm16 + fg * 4 + r;
                    if (key > qrow || key >= kend) sa[g][r] = -1e30f;
                }
        }

        float pr[2][4];
        for (int g = 0; g < 2; ++g)
            for (int r = 0; r < 4; ++r)
                pr[g][r] = __builtin_amdgcn_exp2f(sa[g][r] * k1);
        for (int r = 0; r < 4; ++r) rs[r] += pr[0][r] + pr[1][r];
        for (int g = 0; g < 2; ++g)
            for (int r = 0; r < 4; ++r)
                Pw[(fg * 4 + r) * 40 + g * 16 + fr] =
                    (unsigned short)(__float_as_uint(pr[g][r]) >> 16);

        s16x8 pa = *(const s16x8*)(Pw + fr * 40 + fg * 8);
        for (int t = 0; t < 5; ++t)
            O[t] = __builtin_amdgcn_mfma_f32_16x16x32_bf16(pa, vb[t], O[t], 0, 0, 0);

        kptr += 3072;   // 32 keys * 96
        vptr += 2560;   // 2 blocks * 1280
    }

    for (int r = 0; r < 4; ++r) {
        float v = rs[r];
        v += __shfl_xor(v, 1);
        v += __shfl_xor(v, 2);
        v += __shfl_xor(v, 4);
        v += __shfl_xor(v, 8);
        rs[r] = v;
    }

    if (j) {
        for (int t = 0; t < 5; ++t)
            for (int r = 0; r < 4; ++r)
                parts[slot][fg * 4 + r][t * 16 + fr] = O[t][r];
        if (fr == 0)
            for (int r = 0; r < 4; ++r) parts_l[slot][fg * 4 + r] = rs[r];
    }
    __syncthreads();
    if (!j) {
        for (int r = 0; r < 4; ++r) {
            float rl = 1.0f / (rs[r] + parts_l[slot][fg * 4 + r]);
            int row = sm16 + fg * 4 + r;
            for (int t = 0; t < 5; ++t) {
                float v = (O[t][r] + parts[slot][fg * 4 + r][t * 16 + fr]) * rl;
                attn[(size_t)row * 2560 + h * 80 + t * 16 + fr] = f2bf(v);
            }
        }
    }
}

extern "C" void kernel_launch(void* const* d_in, const int* in_sizes, int n_in,
                              void* d_out, int out_size, void* d_ws, size_t ws_size,
                              hipStream_t stream) {
    const float* x    = (const float*)d_in[0];
    const float* wqkv = (const float*)d_in[1];
    const float* bqkv = (const float*)d_in[2];
    const float* outw = (const float*)d_in[3];
    const float* outb = (const float*)d_in[4];

    unsigned short* xb    = (unsigned short*)d_ws;                  // 2048*2560
    unsigned short* wqkvb = xb + (size_t)2048 * 2560;               // 7680*2560 (dead after gemm1)
    unsigned short* Kp    = wqkvb;                                  // 32*2048*96   (aliases wqkvb)
    unsigned short* Vp    = wqkvb + (size_t)32 * 2048 * 96;         // 32*128*1280  (aliases wqkvb)
    unsigned short* outwb = wqkvb + (size_t)7680 * 2560;            // 2560*2560
    unsigned short* qkvb  = outwb + (size_t)2560 * 2560;            // 2048*7680
    unsigned short* attnb = qkvb  + (size_t)2048 * 7680;            // 2048*2560
    float* out = (float*)d_out;

    cast_bf16_kernel<<<2048 * 2560 / 4 / 256, 256, 0, stream>>>(x, xb, 2048 * 2560 / 4);
    cast_bf16_kernel<<<7680 * 2560 / 4 / 256, 256, 0, stream>>>(wqkv, wqkvb, 7680 * 2560 / 4);
    cast_bf16_kernel<<<2560 * 2560 / 4 / 256, 256, 0, stream>>>(outw, outwb, 2560 * 2560 / 4);

    gemm_bt<true><<<dim3(7680 / 128, 2048 / 128), 256, 0, stream>>>(
        xb, wqkvb, bqkv, (void*)qkvb, 2048, 7680, 2560);

    rope_q_kernel<<<2048 * 64 / 256, 256, 0, stream>>>(qkvb);
    rope_pack_k_kernel<<<2048 * 384 / 256, 256, 0, stream>>>(qkvb, Kp);
    pack_v_kernel<<<32 * 32, 256, 0, stream>>>(qkvb, Vp);

    flash3_kernel<<<2048, 256, 0, stream>>>(qkvb, Kp, Vp, attnb);

    gemm_bt<false><<<dim3(2560 / 128, 2048 / 128), 256, 0, stream>>>(
        attnb, outwb, outb, (void*)out, 2048, 2560, 2560);
}